// Round 4
// baseline (242.317 us; speedup 1.0000x reference)
//
#include <hip/hip_runtime.h>
#include <stdint.h>

#define DD 1024
#define MROWS 32768

typedef __attribute__((ext_vector_type(8))) short short8;
typedef __attribute__((ext_vector_type(8))) unsigned short ushort8;
typedef __attribute__((ext_vector_type(4))) float f32x4;

static __device__ __forceinline__ unsigned short f2bf(float f) {
    union { float f; uint32_t u; } c;
    c.f = f;
    uint32_t u = c.u;
    u += 0x7FFFu + ((u >> 16) & 1u);   // round-to-nearest-even
    return (unsigned short)(u >> 16);
}

static __device__ __forceinline__ void gload_lds16(const void* g, void* l) {
    __builtin_amdgcn_global_load_lds(
        (const __attribute__((address_space(1))) uint32_t*)g,
        (__attribute__((address_space(3))) uint32_t*)l,
        16, 0, 0);
}

// Reconstruct w = th*sign*(th>0), cast to bf16, store TRANSPOSED: wT[n][k] = w[k][n].
__global__ __launch_bounds__(256) void build_wT_kernel(
        const float* __restrict__ th1, const float* __restrict__ sg1,
        const float* __restrict__ th2, const float* __restrict__ sg2,
        unsigned short* __restrict__ wT1, unsigned short* __restrict__ wT2) {
    __shared__ unsigned short tile[64][65];
    const float* th = blockIdx.z ? th2 : th1;
    const float* sg = blockIdx.z ? sg2 : sg1;
    unsigned short* wT = blockIdx.z ? wT2 : wT1;
    const int bk = blockIdx.x;  // k-tile index
    const int bn = blockIdx.y;  // n-tile index
    const int t = threadIdx.x;
    #pragma unroll
    for (int i = 0; i < 4; ++i) {
        int idx = i * 256 + t;
        int r  = idx >> 4;   // k within tile (0..63)
        int cg = idx & 15;   // 4-col group (n)
        size_t base = (size_t)(bk * 64 + r) * DD + bn * 64 + cg * 4;
        const float4 tv = *(const float4*)&th[base];
        const float4 sv = *(const float4*)&sg[base];
        tile[r][cg * 4 + 0] = f2bf(tv.x > 0.f ? tv.x * sv.x : 0.f);
        tile[r][cg * 4 + 1] = f2bf(tv.y > 0.f ? tv.y * sv.y : 0.f);
        tile[r][cg * 4 + 2] = f2bf(tv.z > 0.f ? tv.z * sv.z : 0.f);
        tile[r][cg * 4 + 3] = f2bf(tv.w > 0.f ? tv.w * sv.w : 0.f);
    }
    __syncthreads();
    #pragma unroll
    for (int i = 0; i < 4; ++i) {
        int idx = i * 256 + t;
        int nr = idx >> 4;   // n within tile (0..63)
        int kg = idx & 15;   // 4-k group
        uint32_t lo = tile[kg * 4 + 0][nr] | ((uint32_t)tile[kg * 4 + 1][nr] << 16);
        uint32_t hi = tile[kg * 4 + 2][nr] | ((uint32_t)tile[kg * 4 + 3][nr] << 16);
        *(uint2*)&wT[(size_t)(bn * 64 + nr) * DD + bk * 64 + kg * 4] = make_uint2(lo, hi);
    }
}

// C[m][n] = relu(A[m][:] . B^T[n][:]) — verified m97-structure: 128x128 tile,
// BK=32, 4 waves of 64x64, v_mfma_f32_16x16x32_bf16, global_load_lds staging,
// multi-block/CU occupancy does the latency hiding.
// T1: XCD-chunked bn-minor block swizzle (grid 2048 = 256 bm x 8 bn, %8==0 -> bijective).
// A_FP32: A is fp32 (x), reg-staged with fp32->bf16 convert. Else bf16 via global_load_lds.
// STORE_BF16: ReLU + bf16 store (intermediate Y1); else ReLU + fp32 store.
template<bool A_FP32, bool STORE_BF16>
__global__ __launch_bounds__(256) void gemm_bt(
        const void* __restrict__ Ap,
        const unsigned short* __restrict__ Bt,   // [1024 n][1024 k] bf16
        void* __restrict__ Cp) {
    __shared__ unsigned short sA[128 * 32];   // [row m][k] bf16
    __shared__ unsigned short sB[128 * 32];   // [row n][k] bf16

    const int tid  = threadIdx.x;
    const int lane = tid & 63;
    const int wid  = tid >> 6;       // 0..3
    // T1 XCD swizzle: s%8 = XCD id; each XCD gets a contiguous L-chunk of 256
    // blocks = 32 bm-panels x 8 bn (bn-minor -> A-panel sharers co-XCD).
    const int s = blockIdx.x;
    const int L = ((s & 7) << 8) + (s >> 3);
    const int bm = L >> 3;
    const int bn = L & 7;
    const int wm   = wid >> 1;       // 0..1
    const int wn   = wid & 1;        // 0..1

    const f32x4 vzero = {0.f, 0.f, 0.f, 0.f};
    f32x4 acc[4][4];
    #pragma unroll
    for (int i = 0; i < 4; ++i)
        #pragma unroll
        for (int j = 0; j < 4; ++j) acc[i][j] = vzero;

    // global_load_lds staging addresses (wave-uniform LDS base + lane*16B)
    const int l4r = lane >> 2;       // row within 16-row chunk
    const int l4c = lane & 3;        // 8-elem k group
    const unsigned short* bsrc =
        &Bt[(size_t)(bn * 128 + wid * 32 + l4r) * DD + l4c * 8];
    const unsigned short* asrcb = nullptr;
    const float* af32 = nullptr;
    if (A_FP32) {
        af32 = (const float*)Ap;
    } else {
        asrcb = &((const unsigned short*)Ap)[(size_t)(bm * 128 + wid * 32 + l4r) * DD + l4c * 8];
    }

    // fragment read bases
    const int fr = lane & 15, fq = lane >> 4;
    const unsigned short* sAr = &sA[(wm * 64 + fr) * 32 + fq * 8];
    const unsigned short* sBr = &sB[(wn * 64 + fr) * 32 + fq * 8];

    for (int k0 = 0; k0 < DD; k0 += 32) {
        // ---- stage B (and A) tiles ----
        gload_lds16(bsrc + k0,            &sB[(wid * 32) * 32]);
        gload_lds16(bsrc + 16 * DD + k0,  &sB[(wid * 32 + 16) * 32]);
        if (A_FP32) {
            #pragma unroll
            for (int i = 0; i < 2; ++i) {
                int idx = i * 256 + tid;
                int row = idx >> 2;      // 0..127
                int cg  = idx & 3;       // 8-col group
                const float4* p = (const float4*)&af32[(size_t)(bm * 128 + row) * DD + k0 + cg * 8];
                float4 v0 = p[0], v1 = p[1];
                ushort8 w;
                w[0] = f2bf(v0.x); w[1] = f2bf(v0.y); w[2] = f2bf(v0.z); w[3] = f2bf(v0.w);
                w[4] = f2bf(v1.x); w[5] = f2bf(v1.y); w[6] = f2bf(v1.z); w[7] = f2bf(v1.w);
                *(ushort8*)&sA[row * 32 + cg * 8] = w;
            }
        } else {
            gload_lds16(asrcb + k0,           &sA[(wid * 32) * 32]);
            gload_lds16(asrcb + 16 * DD + k0, &sA[(wid * 32 + 16) * 32]);
        }
        __syncthreads();

        // ---- fragments + 16 MFMA ----
        short8 av[4], bv[4];
        #pragma unroll
        for (int mi = 0; mi < 4; ++mi) av[mi] = *(const short8*)(sAr + mi * 512);
        #pragma unroll
        for (int ni = 0; ni < 4; ++ni) bv[ni] = *(const short8*)(sBr + ni * 512);
        #pragma unroll
        for (int mi = 0; mi < 4; ++mi)
            #pragma unroll
            for (int ni = 0; ni < 4; ++ni)
                acc[mi][ni] = __builtin_amdgcn_mfma_f32_16x16x32_bf16(
                    av[mi], bv[ni], acc[mi][ni], 0, 0, 0);
        __syncthreads();
    }

    // ---- epilogue: ReLU + store ----
    const int orow0 = bm * 128 + wm * 64 + fq * 4;
    const int ocol0 = bn * 128 + wn * 64 + fr;
    #pragma unroll
    for (int mi = 0; mi < 4; ++mi)
        #pragma unroll
        for (int ni = 0; ni < 4; ++ni)
            #pragma unroll
            for (int r = 0; r < 4; ++r) {
                float v = fmaxf(acc[mi][ni][r], 0.f);
                size_t off = (size_t)(orow0 + mi * 16 + r) * DD + (ocol0 + ni * 16);
                if (STORE_BF16) ((unsigned short*)Cp)[off] = f2bf(v);
                else            ((float*)Cp)[off] = v;
            }
}

// Safety net if d_ws is too small: fused fp32 VALU path, no workspace.
__global__ __launch_bounds__(256) void fallback_fused(
        const float* __restrict__ x,
        const float* __restrict__ th1, const float* __restrict__ sg1,
        const float* __restrict__ th2, const float* __restrict__ sg2,
        float* __restrict__ out) {
    __shared__ float xr[8][DD];
    __shared__ float y1[8][DD];
    const int rb = blockIdx.x * 8;
    const int t = threadIdx.x;
    for (int r = 0; r < 8; ++r)
        for (int i = t; i < DD; i += 256)
            xr[r][i] = x[(size_t)(rb + r) * DD + i];
    __syncthreads();
    for (int jo = 0; jo < 4; ++jo) {
        const int j = jo * 256 + t;
        float a[8] = {0, 0, 0, 0, 0, 0, 0, 0};
        for (int k = 0; k < DD; ++k) {
            float tv = th1[(size_t)k * DD + j];
            float w = tv > 0.f ? tv * sg1[(size_t)k * DD + j] : 0.f;
            #pragma unroll
            for (int r = 0; r < 8; ++r) a[r] += xr[r][k] * w;
        }
        #pragma unroll
        for (int r = 0; r < 8; ++r) y1[r][j] = fmaxf(a[r], 0.f);
    }
    __syncthreads();
    for (int jo = 0; jo < 4; ++jo) {
        const int j = jo * 256 + t;
        float a[8] = {0, 0, 0, 0, 0, 0, 0, 0};
        for (int k = 0; k < DD; ++k) {
            float tv = th2[(size_t)k * DD + j];
            float w = tv > 0.f ? tv * sg2[(size_t)k * DD + j] : 0.f;
            #pragma unroll
            for (int r = 0; r < 8; ++r) a[r] += y1[r][k] * w;
        }
        #pragma unroll
        for (int r = 0; r < 8; ++r) out[(size_t)(rb + r) * DD + j] = fmaxf(a[r], 0.f);
    }
}

extern "C" void kernel_launch(void* const* d_in, const int* in_sizes, int n_in,
                              void* d_out, int out_size, void* d_ws, size_t ws_size,
                              hipStream_t stream) {
    const float* x   = (const float*)d_in[0];
    const float* th1 = (const float*)d_in[1];
    const float* sg1 = (const float*)d_in[2];
    const float* th2 = (const float*)d_in[3];
    const float* sg2 = (const float*)d_in[4];
    float* out = (float*)d_out;

    const size_t need = ((size_t)2 * 1024 * 1024 + (size_t)MROWS * 1024) * 2;  // wT1+wT2+Y1 bf16
    if (ws_size >= need) {
        unsigned short* wT1 = (unsigned short*)d_ws;
        unsigned short* wT2 = wT1 + 1024 * 1024;
        unsigned short* Y1  = wT2 + 1024 * 1024;
        build_wT_kernel<<<dim3(16, 16, 2), 256, 0, stream>>>(th1, sg1, th2, sg2, wT1, wT2);
        gemm_bt<true,  true ><<<dim3((MROWS / 128) * 8), 256, 0, stream>>>(x,  wT1, Y1);
        gemm_bt<false, false><<<dim3((MROWS / 128) * 8), 256, 0, stream>>>(Y1, wT2, out);
    } else {
        fallback_fused<<<MROWS / 8, 256, 0, stream>>>(x, th1, sg1, th2, sg2, out);
    }
}

// Round 5
// 240.642 us; speedup vs baseline: 1.0070x; 1.0070x over previous
//
#include <hip/hip_runtime.h>
#include <stdint.h>

#define DD 1024
#define MROWS 32768
#define NTK 32   // K-tiles: 1024 / 32

typedef __attribute__((ext_vector_type(8))) short short8;
typedef __attribute__((ext_vector_type(8))) unsigned short ushort8;
typedef __attribute__((ext_vector_type(4))) float f32x4;

static __device__ __forceinline__ unsigned short f2bf(float f) {
    union { float f; uint32_t u; } c;
    c.f = f;
    uint32_t u = c.u;
    u += 0x7FFFu + ((u >> 16) & 1u);   // round-to-nearest-even
    return (unsigned short)(u >> 16);
}

static __device__ __forceinline__ void gload_lds16(const void* g, void* l) {
    __builtin_amdgcn_global_load_lds(
        (const __attribute__((address_space(1))) uint32_t*)g,
        (__attribute__((address_space(3))) uint32_t*)l,
        16, 0, 0);
}

#define SBAR() __builtin_amdgcn_s_barrier()
#define SCHED_FENCE() __builtin_amdgcn_sched_barrier(0)

// Reconstruct w = th*sign*(th>0), cast to bf16, store TRANSPOSED: wT[n][k] = w[k][n].
__global__ __launch_bounds__(256) void build_wT_kernel(
        const float* __restrict__ th1, const float* __restrict__ sg1,
        const float* __restrict__ th2, const float* __restrict__ sg2,
        unsigned short* __restrict__ wT1, unsigned short* __restrict__ wT2) {
    __shared__ unsigned short tile[64][65];
    const float* th = blockIdx.z ? th2 : th1;
    const float* sg = blockIdx.z ? sg2 : sg1;
    unsigned short* wT = blockIdx.z ? wT2 : wT1;
    const int bk = blockIdx.x, bn = blockIdx.y, t = threadIdx.x;
    #pragma unroll
    for (int i = 0; i < 4; ++i) {
        int idx = i * 256 + t;
        int r = idx >> 4, cg = idx & 15;
        size_t base = (size_t)(bk * 64 + r) * DD + bn * 64 + cg * 4;
        const float4 tv = *(const float4*)&th[base];
        const float4 sv = *(const float4*)&sg[base];
        tile[r][cg * 4 + 0] = f2bf(tv.x > 0.f ? tv.x * sv.x : 0.f);
        tile[r][cg * 4 + 1] = f2bf(tv.y > 0.f ? tv.y * sv.y : 0.f);
        tile[r][cg * 4 + 2] = f2bf(tv.z > 0.f ? tv.z * sv.z : 0.f);
        tile[r][cg * 4 + 3] = f2bf(tv.w > 0.f ? tv.w * sv.w : 0.f);
    }
    __syncthreads();
    #pragma unroll
    for (int i = 0; i < 4; ++i) {
        int idx = i * 256 + t;
        int nr = idx >> 4, kg = idx & 15;
        uint32_t lo = tile[kg * 4 + 0][nr] | ((uint32_t)tile[kg * 4 + 1][nr] << 16);
        uint32_t hi = tile[kg * 4 + 2][nr] | ((uint32_t)tile[kg * 4 + 3][nr] << 16);
        *(uint2*)&wT[(size_t)(bn * 64 + nr) * DD + bk * 64 + kg * 4] = make_uint2(lo, hi);
    }
}

// Double-buffered 128x128 GEMM, BK=32, 4 waves, full-tile vmcnt slack.
// C[m][n] = relu(A[m][:] . Bt[n][:])
// A_FP32: A staged as fp32 via global_load_lds, converted at fragment read.
template<bool A_FP32>
__global__ __launch_bounds__(256, A_FP32 ? 3 : 4) void gemm_db(
        const void* __restrict__ Ap,
        const unsigned short* __restrict__ Bt,   // [1024 n][1024 k] bf16
        void* __restrict__ Cp) {
    __shared__ unsigned short sB[2][128 * 32];                  // 8 KiB x2
    __shared__ float          sAf[A_FP32 ? 2 * 128 * 32 : 2];   // 16 KiB x2 | -
    __shared__ unsigned short sAh[A_FP32 ? 2 : 2 * 128 * 32];   // - | 8 KiB x2

    const int tid  = threadIdx.x;
    const int lane = tid & 63;
    const int wid  = tid >> 6;       // 0..3
    const int wm = wid >> 1, wn = wid & 1;
    const int fr = lane & 15, fq = lane >> 4;

    // T1: XCD-chunked bn-minor swizzle (2048 blocks: 256 bm x 8 bn)
    const int s = blockIdx.x;
    const int L = ((s & 7) << 8) + (s >> 3);
    const int bm = L >> 3;
    const int bn = L & 7;

    // ---- staging sources (pre-swizzled global slot = involution of read XOR) ----
    // B/A-bf16: rows w*32 + j*16 + (lane>>2); 16B slot (lane&3) ^ ((lane>>2)&3)
    const unsigned short* bsrc =
        Bt + (size_t)(bn * 128 + wid * 32 + (lane >> 2)) * DD
           + ((lane & 3) ^ ((lane >> 2) & 3)) * 8;
    const unsigned short* ahsrc = nullptr;
    const float* afsrc = nullptr;
    if constexpr (A_FP32) {
        // fp32 rows w*32 + j*8 + (lane>>3); 16B slot (lane&7) ^ ((lane>>3)&7)
        afsrc = (const float*)Ap + (size_t)(bm * 128 + wid * 32 + (lane >> 3)) * DD
                                 + ((lane & 7) ^ ((lane >> 3) & 7)) * 4;
    } else {
        ahsrc = (const unsigned short*)Ap + (size_t)(bm * 128 + wid * 32 + (lane >> 2)) * DD
                                          + ((lane & 3) ^ ((lane >> 2) & 3)) * 8;
    }

    auto stage = [&](int p, int kt) {
        #pragma unroll
        for (int j = 0; j < 2; ++j)
            gload_lds16(bsrc + (size_t)j * 16 * DD + kt * 32,
                        &sB[p][(wid * 32 + j * 16) * 32]);
        if constexpr (A_FP32) {
            #pragma unroll
            for (int j = 0; j < 4; ++j)
                gload_lds16(afsrc + (size_t)j * 8 * DD + kt * 32,
                            &sAf[(size_t)p * 128 * 32 + (wid * 32 + j * 8) * 32]);
        } else {
            #pragma unroll
            for (int j = 0; j < 2; ++j)
                gload_lds16(ahsrc + (size_t)j * 16 * DD + kt * 32,
                            &sAh[(size_t)p * 128 * 32 + (wid * 32 + j * 16) * 32]);
        }
    };

    const f32x4 vz = {0.f, 0.f, 0.f, 0.f};
    f32x4 acc[4][4];
    #pragma unroll
    for (int i = 0; i < 4; ++i)
        #pragma unroll
        for (int j = 0; j < 4; ++j) acc[i][j] = vz;

    stage(0, 0);   // prologue

    #pragma unroll 1
    for (int t = 0; t < NTK; ++t) {
        const int p = t & 1;
        if (t + 1 < NTK) {
            stage(p ^ 1, t + 1);
            // wait stage(t) complete: allow the loads just issued to stay in flight
            if constexpr (A_FP32) asm volatile("s_waitcnt vmcnt(6)" ::: "memory");
            else                  asm volatile("s_waitcnt vmcnt(4)" ::: "memory");
        } else {
            asm volatile("s_waitcnt vmcnt(0)" ::: "memory");
        }
        SBAR();          // all waves' stages for tile t visible
        SCHED_FENCE();   // keep ds_reads below the barrier

        // ---- fragments (T2-swizzled reads) + 16 MFMA ----
        short8 av[4], bv[4];
        #pragma unroll
        for (int ni = 0; ni < 4; ++ni) {
            int row = wn * 64 + ni * 16 + fr;
            bv[ni] = *(const short8*)((const char*)&sB[p][0]
                        + row * 64 + ((fq ^ (row & 3)) << 4));
        }
        if constexpr (A_FP32) {
            #pragma unroll
            for (int mi = 0; mi < 4; ++mi) {
                int row = wm * 64 + mi * 16 + fr;
                const char* base = (const char*)&sAf[(size_t)p * 128 * 32] + row * 128;
                f32x4 lo = *(const f32x4*)(base + ((((fq << 1) | 0) ^ (row & 7)) << 4));
                f32x4 hi = *(const f32x4*)(base + ((((fq << 1) | 1) ^ (row & 7)) << 4));
                short8 w;
                #pragma unroll
                for (int i = 0; i < 4; ++i) { w[i] = (short)f2bf(lo[i]); w[4 + i] = (short)f2bf(hi[i]); }
                av[mi] = w;
            }
        } else {
            #pragma unroll
            for (int mi = 0; mi < 4; ++mi) {
                int row = wm * 64 + mi * 16 + fr;
                av[mi] = *(const short8*)((const char*)&sAh[(size_t)p * 128 * 32]
                            + row * 64 + ((fq ^ (row & 3)) << 4));
            }
        }
        #pragma unroll
        for (int mi = 0; mi < 4; ++mi)
            #pragma unroll
            for (int ni = 0; ni < 4; ++ni)
                acc[mi][ni] = __builtin_amdgcn_mfma_f32_16x16x32_bf16(
                    av[mi], bv[ni], acc[mi][ni], 0, 0, 0);
        SBAR();          // close reads of buffer p (next iter overwrites it)
    }

    // ---- epilogue: ReLU + store ----
    const int orow0 = bm * 128 + wm * 64 + fq * 4;
    const int ocol0 = bn * 128 + wn * 64 + fr;
    #pragma unroll
    for (int mi = 0; mi < 4; ++mi)
        #pragma unroll
        for (int ni = 0; ni < 4; ++ni)
            #pragma unroll
            for (int r = 0; r < 4; ++r) {
                float v = fmaxf(acc[mi][ni][r], 0.f);
                size_t off = (size_t)(orow0 + mi * 16 + r) * DD + (ocol0 + ni * 16);
                if (A_FP32) ((unsigned short*)Cp)[off] = f2bf(v);
                else        ((float*)Cp)[off] = v;
            }
}

// Safety net if d_ws is too small: fused fp32 VALU path, no workspace.
__global__ __launch_bounds__(256) void fallback_fused(
        const float* __restrict__ x,
        const float* __restrict__ th1, const float* __restrict__ sg1,
        const float* __restrict__ th2, const float* __restrict__ sg2,
        float* __restrict__ out) {
    __shared__ float xr[8][DD];
    __shared__ float y1[8][DD];
    const int rb = blockIdx.x * 8;
    const int t = threadIdx.x;
    for (int r = 0; r < 8; ++r)
        for (int i = t; i < DD; i += 256)
            xr[r][i] = x[(size_t)(rb + r) * DD + i];
    __syncthreads();
    for (int jo = 0; jo < 4; ++jo) {
        const int j = jo * 256 + t;
        float a[8] = {0, 0, 0, 0, 0, 0, 0, 0};
        for (int k = 0; k < DD; ++k) {
            float tv = th1[(size_t)k * DD + j];
            float w = tv > 0.f ? tv * sg1[(size_t)k * DD + j] : 0.f;
            #pragma unroll
            for (int r = 0; r < 8; ++r) a[r] += xr[r][k] * w;
        }
        #pragma unroll
        for (int r = 0; r < 8; ++r) y1[r][j] = fmaxf(a[r], 0.f);
    }
    __syncthreads();
    for (int jo = 0; jo < 4; ++jo) {
        const int j = jo * 256 + t;
        float a[8] = {0, 0, 0, 0, 0, 0, 0, 0};
        for (int k = 0; k < DD; ++k) {
            float tv = th2[(size_t)k * DD + j];
            float w = tv > 0.f ? tv * sg2[(size_t)k * DD + j] : 0.f;
            #pragma unroll
            for (int r = 0; r < 8; ++r) a[r] += y1[r][k] * w;
        }
        #pragma unroll
        for (int r = 0; r < 8; ++r) out[(size_t)(rb + r) * DD + j] = fmaxf(a[r], 0.f);
    }
}

extern "C" void kernel_launch(void* const* d_in, const int* in_sizes, int n_in,
                              void* d_out, int out_size, void* d_ws, size_t ws_size,
                              hipStream_t stream) {
    const float* x   = (const float*)d_in[0];
    const float* th1 = (const float*)d_in[1];
    const float* sg1 = (const float*)d_in[2];
    const float* th2 = (const float*)d_in[3];
    const float* sg2 = (const float*)d_in[4];
    float* out = (float*)d_out;

    const size_t need = ((size_t)2 * 1024 * 1024 + (size_t)MROWS * 1024) * 2;  // wT1+wT2+Y1 bf16
    if (ws_size >= need) {
        unsigned short* wT1 = (unsigned short*)d_ws;
        unsigned short* wT2 = wT1 + 1024 * 1024;
        unsigned short* Y1  = wT2 + 1024 * 1024;
        build_wT_kernel<<<dim3(16, 16, 2), 256, 0, stream>>>(th1, sg1, th2, sg2, wT1, wT2);
        gemm_db<true ><<<dim3((MROWS / 128) * 8), 256, 0, stream>>>(x,  wT1, Y1);
        gemm_db<false><<<dim3((MROWS / 128) * 8), 256, 0, stream>>>(Y1, wT2, out);
    } else {
        fallback_fused<<<MROWS / 8, 256, 0, stream>>>(x, th1, sg1, th2, sg2, out);
    }
}